// Round 10
// baseline (123.532 us; speedup 1.0000x reference)
//
#include <hip/hip_runtime.h>
#include <math.h>

// Problem constants
#define B_  32
#define S_  2048
#define D_  512
#define A_  256
#define BS_ (B_ * S_)

// ws layout (float offsets)
#define WEFF_OFF  0                   // 256 floats
#define DEC_OFF   256                 // B*A = 8192
#define EPART_OFF 8448                // B*S = 65536 floats
#define CTX_OFF   (8448 + BS_)        // 32*B*D = 524288 floats; start reused as W16 (f16)

typedef _Float16 f16x8 __attribute__((ext_vector_type(8)));
typedef __fp16   fp16x2 __attribute__((ext_vector_type(2)));
typedef _Float16 half4 __attribute__((ext_vector_type(4)));
typedef float floatx4 __attribute__((ext_vector_type(4)));

__device__ __forceinline__ void glds16(const void* g, void* l) {
    __builtin_amdgcn_global_load_lds(
        (const __attribute__((address_space(1))) void*)g,
        (__attribute__((address_space(3))) void*)l, 16, 0, 0);
}

// ---------------------------------------------------------------------------
// Merged prep: block 0 = weff, blocks 1..32 = dec_term, blocks 33..160 = W->f16
__global__ void ma_prep_kernel(const float* __restrict__ v_w,
                               const float* __restrict__ v_g,
                               const float* __restrict__ dec,
                               const float* __restrict__ V,
                               const float* __restrict__ bvec,
                               const float* __restrict__ W,
                               _Float16* __restrict__ W16,
                               float* __restrict__ ws) {
    __shared__ float sh[D_];
    const int bid = blockIdx.x, t = threadIdx.x;
    if (bid == 0) {
        float v = v_w[t];
        float sq = v * v;
        #pragma unroll
        for (int off = 32; off > 0; off >>= 1) sq += __shfl_down(sq, off, 64);
        if ((t & 63) == 0) sh[t >> 6] = sq;
        __syncthreads();
        float n2 = sh[0] + sh[1] + sh[2] + sh[3];
        ws[WEFF_OFF + t] = v_g[0] * v / sqrtf(n2);
    } else if (bid <= B_) {
        const int b = bid - 1;
        sh[t]       = dec[b * D_ + t];
        sh[t + 256] = dec[b * D_ + 256 + t];
        __syncthreads();
        const float4* Vr = (const float4*)(V + (size_t)t * D_);
        float acc = 0.f;
        #pragma unroll 4
        for (int k = 0; k < D_ / 4; ++k) {
            float4 v4 = Vr[k];
            acc = fmaf(v4.x, sh[4*k+0], acc);
            acc = fmaf(v4.y, sh[4*k+1], acc);
            acc = fmaf(v4.z, sh[4*k+2], acc);
            acc = fmaf(v4.w, sh[4*k+3], acc);
        }
        ws[DEC_OFF + b * A_ + t] = acc + bvec[t];
    } else {
        int i = (bid - (B_ + 1)) * 256 + t;
        float4 v = ((const float4*)W)[i];
        half4 h;
        h[0] = (_Float16)v.x; h[1] = (_Float16)v.y;
        h[2] = (_Float16)v.z; h[3] = (_Float16)v.w;
        ((half4*)W16)[i] = h;
    }
}

// ---------------------------------------------------------------------------
// Energy: B-LDS-resident, barrier-free K loop.
// Block = 128 rows x 256 a-cols, 8 waves (2 wm x 4 wn), each 64x64.
// Two K-phases of 256: stage B half [256a][256k] (128 KB) via glds
// (pre-swizzled source, c^(row&7)) -> barrier -> 8 BK=32 iters with NO
// barriers: A streamed from global into named double-buffer regs (pA/pB),
// f32->f16 at consume (cvt_pkrtz). LDS 128 KB -> 1 block/CU, 2 waves/EU;
// launch_bounds(512,2) -> 256-VGPR budget, no spill.
__global__ __launch_bounds__(512, 2) void ma_energy_mfma(
        const float* __restrict__ enc,
        const _Float16* __restrict__ W16,
        const float* __restrict__ ws_in,
        float* __restrict__ energy) {
    __shared__ __align__(16) _Float16 Bsm[65536];   // 128 KB

    const int t  = threadIdx.x;
    const int bx = blockIdx.x;             // 512 tiles of 128 rows
    const size_t R0 = (size_t)bx * 128;
    const int batch = bx >> 4;             // 16 tiles per batch

    const int lane = t & 63, wid = t >> 6;
    const int wm = wid >> 2, wn = wid & 3;
    const int fr = lane & 15, kq = lane >> 4;

    // A stream base: rows wm*64 + m*16 + fr, k = gk*32 + kq*8
    const float* Ag = enc + (R0 + wm * 64 + (size_t)fr) * D_ + kq * 8;

    floatx4 acc[4][4];
    #pragma unroll
    for (int m = 0; m < 4; ++m)
        #pragma unroll
        for (int n = 0; n < 4; ++n) acc[m][n] = (floatx4)0.f;

#define STAGEB(phase) do { \
        _Pragma("unroll") \
        for (int j = 0; j < 16; ++j) { \
            const int p   = (wid * 16 + j) * 64 + lane; \
            const int row = p >> 5, cc = p & 31; \
            glds16(W16 + (size_t)row * D_ + (phase) * 256 + ((cc ^ (row & 7)) * 8), \
                   &Bsm[(wid * 16 + j) * 512]); \
        } } while (0)

#define LOADA(buf, gk) do { \
        _Pragma("unroll") \
        for (int m = 0; m < 4; ++m) { \
            buf[m][0] = *(const float4*)(Ag + m * 16 * D_ + (gk) * 32); \
            buf[m][1] = *(const float4*)(Ag + m * 16 * D_ + (gk) * 32 + 4); \
        } } while (0)

#define SUBITER(buf, kt, gk) do { \
        f16x8 af[4], bf[4]; \
        _Pragma("unroll") \
        for (int m = 0; m < 4; ++m) { \
            union { fp16x2 h2[4]; f16x8 v; } u; \
            u.h2[0] = __builtin_amdgcn_cvt_pkrtz(buf[m][0].x, buf[m][0].y); \
            u.h2[1] = __builtin_amdgcn_cvt_pkrtz(buf[m][0].z, buf[m][0].w); \
            u.h2[2] = __builtin_amdgcn_cvt_pkrtz(buf[m][1].x, buf[m][1].y); \
            u.h2[3] = __builtin_amdgcn_cvt_pkrtz(buf[m][1].z, buf[m][1].w); \
            af[m] = u.v; \
        } \
        if ((gk) + 2 < 16) LOADA(buf, (gk) + 2); \
        _Pragma("unroll") \
        for (int n = 0; n < 4; ++n) { \
            const int row = wn * 64 + n * 16 + fr; \
            const int cc  = (kt) * 4 + kq; \
            bf[n] = *(const f16x8*)&Bsm[row * 256 + ((cc ^ (row & 7)) * 8)]; \
        } \
        _Pragma("unroll") \
        for (int m = 0; m < 4; ++m) \
            _Pragma("unroll") \
            for (int n = 0; n < 4; ++n) \
                acc[m][n] = __builtin_amdgcn_mfma_f32_16x16x32_f16(af[m], bf[n], acc[m][n], 0, 0, 0); \
    } while (0)

    float4 pA[4][2], pB[4][2];
    LOADA(pA, 0);
    LOADA(pB, 1);

    #pragma unroll
    for (int phase = 0; phase < 2; ++phase) {
        if (phase) __syncthreads();        // all waves done reading Bsm phase 0
        STAGEB(phase);
        __syncthreads();                   // glds drained, Bsm ready
        #pragma unroll
        for (int kh = 0; kh < 4; ++kh) {
            SUBITER(pA, 2 * kh,     phase * 8 + 2 * kh);
            SUBITER(pB, 2 * kh + 1, phase * 8 + 2 * kh + 1);
        }
    }
#undef STAGEB
#undef LOADA
#undef SUBITER

    __syncthreads();                       // before red aliases Bsm
    // epilogue: tanh + weighted reduce over all 256 a-cols
    float* const red = (float*)Bsm;        // [4 wn][128 rows]
    const float* weff  = ws_in + WEFF_OFF;
    const float* dterm = ws_in + DEC_OFF + batch * A_;
    float wj[4], dj[4];
    #pragma unroll
    for (int n = 0; n < 4; ++n) {
        int a = wn * 64 + n * 16 + fr;
        wj[n] = weff[a];
        dj[n] = dterm[a];
    }
    #pragma unroll
    for (int m = 0; m < 4; ++m) {
        #pragma unroll
        for (int r = 0; r < 4; ++r) {
            float v = 0.f;
            #pragma unroll
            for (int n = 0; n < 4; ++n) {
                float x = acc[m][n][r] + dj[n];
                float e = __expf(2.f * x);
                v += (1.f - 2.f / (e + 1.f)) * wj[n];   // tanh(x)
            }
            #pragma unroll
            for (int mask = 1; mask < 16; mask <<= 1)
                v += __shfl_xor(v, mask, 64);
            if (fr == 0)
                red[wn * 128 + wm * 64 + m * 16 + (kq << 2) + r] = v;
        }
    }
    __syncthreads();
    if (t < 128)
        energy[R0 + t] = red[t] + red[128 + t] + red[256 + t] + red[384 + t];
}

// ---------------------------------------------------------------------------
// Monotonic recurrence as a stable affine scan:
//   T_j = a_j * T_{j-1} + prev_j,  a_j = clip(1-p_j, 1e-10, 1),  alpha_j = p_j*T_j
__global__ void ma_scan_kernel(const float* __restrict__ energy,
                               const float* __restrict__ noise,
                               const float* __restrict__ prev,
                               const float* __restrict__ v_bias,
                               const float* __restrict__ r,
                               float* __restrict__ alpha_out) {
    int b = blockIdx.x, t = threadIdx.x;   // 256 threads x 8 elems
    const float bias = v_bias[0] + r[0];
    int base = b * S_ + t * 8;
    float p[8], av[8], bv[8];
    #pragma unroll
    for (int i = 0; i < 8; ++i) {
        float e = energy[base + i] + bias + noise[base + i];
        float pi = 1.f / (1.f + expf(-e));
        p[i]  = pi;
        av[i] = fmaxf(1.f - pi, 1e-10f);
        bv[i] = prev[base + i];
    }
    float Ai = 1.f, Bi = 0.f;
    #pragma unroll
    for (int i = 0; i < 8; ++i) { Bi = av[i] * Bi + bv[i]; Ai *= av[i]; }
    int lane = t & 63;
    #pragma unroll
    for (int off = 1; off < 64; off <<= 1) {
        float Ap = __shfl_up(Ai, off, 64);
        float Bp = __shfl_up(Bi, off, 64);
        if (lane >= off) { Bi = Ai * Bp + Bi; Ai = Ai * Ap; }
    }
    __shared__ float wA[4], wB[4];
    int w = t >> 6;
    if (lane == 63) { wA[w] = Ai; wB[w] = Bi; }
    __syncthreads();
    float Ax = __shfl_up(Ai, 1, 64);
    float Bx = __shfl_up(Bi, 1, 64);
    if (lane == 0) { Ax = 1.f; Bx = 0.f; }
    float PwA = 1.f, PwB = 0.f;
    for (int q = 0; q < w; ++q) { PwB = wA[q] * PwB + wB[q]; PwA *= wA[q]; }
    float T = Ax * PwB + Bx;
    #pragma unroll
    for (int i = 0; i < 8; ++i) {
        T = av[i] * T + bv[i];
        alpha_out[base + i] = p[i] * T;
    }
}

// ---------------------------------------------------------------------------
// context partials over s-chunks of 64, float4 loads
__global__ void ma_ctxpart_kernel(const float* __restrict__ enc,
                                  const float* __restrict__ alpha,
                                  float* __restrict__ cpart) {
    int b = blockIdx.x, sc = blockIdx.y, t = threadIdx.x;   // 256 threads
    const int sp = t >> 7;          // row parity
    const int d4 = t & 127;         // float4 column
    const float4* e = (const float4*)(enc + ((size_t)b * S_ + sc * 64) * D_);
    const float* al = alpha + b * S_ + sc * 64;
    float4 acc = {0.f, 0.f, 0.f, 0.f};
    #pragma unroll 4
    for (int s = sp; s < 64; s += 2) {
        float a = al[s];
        float4 v = e[(size_t)s * 128 + d4];
        acc.x = fmaf(v.x, a, acc.x);
        acc.y = fmaf(v.y, a, acc.y);
        acc.z = fmaf(v.z, a, acc.z);
        acc.w = fmaf(v.w, a, acc.w);
    }
    __shared__ float4 sh[128];
    if (sp == 1) sh[d4] = acc;
    __syncthreads();
    if (sp == 0) {
        float4 o = sh[d4];
        acc.x += o.x; acc.y += o.y; acc.z += o.z; acc.w += o.w;
        ((float4*)(cpart + ((size_t)(sc * B_ + b)) * D_))[d4] = acc;
    }
}

__global__ void ma_ctxreduce_kernel(const float* __restrict__ cpart,
                                    float* __restrict__ ctx) {
    int b = blockIdx.x, t = threadIdx.x;
    #pragma unroll
    for (int h = 0; h < 2; ++h) {
        int d = t + h * 256;
        float s = 0.f;
        #pragma unroll
        for (int q = 0; q < 32; ++q) s += cpart[((size_t)(q * B_ + b)) * D_ + d];
        ctx[b * D_ + d] = s;
    }
}

// ---------------------------------------------------------------------------
extern "C" void kernel_launch(void* const* d_in, const int* in_sizes, int n_in,
                              void* d_out, int out_size, void* d_ws, size_t ws_size,
                              hipStream_t stream) {
    const float* enc    = (const float*)d_in[0];
    const float* dec    = (const float*)d_in[1];
    const float* prev   = (const float*)d_in[2];
    const float* noise  = (const float*)d_in[3];
    const float* W      = (const float*)d_in[4];
    const float* V      = (const float*)d_in[5];
    const float* bvec   = (const float*)d_in[6];
    const float* v_w    = (const float*)d_in[7];
    const float* v_g    = (const float*)d_in[8];
    const float* v_bias = (const float*)d_in[9];
    const float* r      = (const float*)d_in[10];

    float* out = (float*)d_out;             // [0:16384) context, [16384:81920) alpha
    float* ws  = (float*)d_ws;
    float* alpha = out + B_ * D_;
    _Float16* W16 = (_Float16*)(ws + CTX_OFF);   // region reused by cpart later

    ma_prep_kernel<<<1 + B_ + 128, 256, 0, stream>>>(v_w, v_g, dec, V, bvec, W, W16, ws);
    ma_energy_mfma<<<512, 512, 0, stream>>>(enc, W16, ws, ws + EPART_OFF);
    ma_scan_kernel<<<B_, 256, 0, stream>>>(ws + EPART_OFF, noise, prev, v_bias, r, alpha);
    dim3 gc(B_, 32);
    ma_ctxpart_kernel<<<gc, 256, 0, stream>>>(enc, alpha, ws + CTX_OFF);
    ma_ctxreduce_kernel<<<B_, 256, 0, stream>>>(ws + CTX_OFF, out);
}

// Round 11
// 77.116 us; speedup vs baseline: 1.6019x; 1.6019x over previous
//
#include <hip/hip_runtime.h>
#include <math.h>

// Problem constants
#define B_  32
#define S_  2048
#define D_  512
#define A_  256
#define BS_ (B_ * S_)

// ws layout (float offsets)
#define WEFF_OFF  0                   // 256 floats
#define DEC_OFF   256                 // B*A = 8192
#define EPART_OFF 8448                // B*S = 65536 floats
#define CTX_OFF   (8448 + BS_)        // cpart 16*B*D = 262144 fl; reused as W16 first

typedef _Float16 f16x8 __attribute__((ext_vector_type(8)));
typedef __fp16   fp16x2 __attribute__((ext_vector_type(2)));
typedef _Float16 half4 __attribute__((ext_vector_type(4)));
typedef float floatx4 __attribute__((ext_vector_type(4)));

__device__ __forceinline__ void glds16(const void* g, void* l) {
    __builtin_amdgcn_global_load_lds(
        (const __attribute__((address_space(1))) void*)g,
        (__attribute__((address_space(3))) void*)l, 16, 0, 0);
}

// ---------------------------------------------------------------------------
// Merged prep: block 0 = weff, blocks 1..32 = dec_term, blocks 33..160 = W->f16
__global__ void ma_prep_kernel(const float* __restrict__ v_w,
                               const float* __restrict__ v_g,
                               const float* __restrict__ dec,
                               const float* __restrict__ V,
                               const float* __restrict__ bvec,
                               const float* __restrict__ W,
                               _Float16* __restrict__ W16,
                               float* __restrict__ ws) {
    __shared__ float sh[D_];
    const int bid = blockIdx.x, t = threadIdx.x;
    if (bid == 0) {
        float v = v_w[t];
        float sq = v * v;
        #pragma unroll
        for (int off = 32; off > 0; off >>= 1) sq += __shfl_down(sq, off, 64);
        if ((t & 63) == 0) sh[t >> 6] = sq;
        __syncthreads();
        float n2 = sh[0] + sh[1] + sh[2] + sh[3];
        ws[WEFF_OFF + t] = v_g[0] * v / sqrtf(n2);
    } else if (bid <= B_) {
        const int b = bid - 1;
        sh[t]       = dec[b * D_ + t];
        sh[t + 256] = dec[b * D_ + 256 + t];
        __syncthreads();
        const float4* Vr = (const float4*)(V + (size_t)t * D_);
        float acc = 0.f;
        #pragma unroll 4
        for (int k = 0; k < D_ / 4; ++k) {
            float4 v4 = Vr[k];
            acc = fmaf(v4.x, sh[4*k+0], acc);
            acc = fmaf(v4.y, sh[4*k+1], acc);
            acc = fmaf(v4.z, sh[4*k+2], acc);
            acc = fmaf(v4.w, sh[4*k+3], acc);
        }
        ws[DEC_OFF + b * A_ + t] = acc + bvec[t];
    } else {
        int i = (bid - (B_ + 1)) * 256 + t;
        float4 v = ((const float4*)W)[i];
        half4 h;
        h[0] = (_Float16)v.x; h[1] = (_Float16)v.y;
        h[2] = (_Float16)v.z; h[3] = (_Float16)v.w;
        ((half4*)W16)[i] = h;
    }
}

// ---------------------------------------------------------------------------
// Energy (R7 structure, verbatim): 128 rows x 256 a-cols, K=512, BK=32.
// 8 waves (2 wm x 4 wn), each 64x64 via 4x4 frags of 16x16x32 f16.
// A (f32) and B (f16) staged via global_load_lds (zero staging registers),
// double-buffered, XOR-swizzled. A converted f32->f16 via cvt_pkrtz.
__global__ __launch_bounds__(512) void ma_energy_mfma(
        const float* __restrict__ enc,
        const _Float16* __restrict__ W16,
        const float* __restrict__ ws_in,
        float* __restrict__ energy) {
    __shared__ __align__(16) float    As[2][128 * 32];   // 16 KB each buf
    __shared__ __align__(16) _Float16 Bs[2][256 * 32];   // 16 KB each buf
    __shared__ float red[4][128];

    const int t  = threadIdx.x;
    const int bx = blockIdx.x;             // 512 tiles of 128 rows
    const size_t R0 = (size_t)bx * 128;
    const int batch = bx >> 4;             // 16 tiles per batch

    const int lane = t & 63, wid = t >> 6;
    const int wm = wid >> 2, wn = wid & 3;
    const int fr = lane & 15, kq = lane >> 4;

    // ---- staging sources (per-lane global addr carries the LDS swizzle) ----
    const int arow = t >> 3, ac = t & 7;
    const float* AgS0 = enc + (R0 + (size_t)arow) * D_ + (ac ^ (arow & 7)) * 4;
    const float* AgS1 = AgS0 + (size_t)64 * D_;          // row+64 keeps row&7
    const int brow = t >> 2, bc = t & 3;
    const _Float16* BgS0 = W16 + (size_t)brow * D_ + (bc ^ ((brow >> 1) & 3)) * 8;
    const _Float16* BgS1 = BgS0 + (size_t)128 * D_;      // row+128 keeps (row>>1)&3

    // ---- frag-read offsets (swizzled) ----
    const int axc0 = ((2 * kq)     ^ (fr & 7)) * 4;
    const int axc1 = ((2 * kq + 1) ^ (fr & 7)) * 4;
    const int bxo  = (kq ^ ((fr >> 1) & 3)) * 8;

    floatx4 acc[4][4];
    #pragma unroll
    for (int m = 0; m < 4; ++m)
        #pragma unroll
        for (int n = 0; n < 4; ++n) acc[m][n] = (floatx4)0.f;

    // prologue: stage k-tile 0 into buf 0
    glds16(AgS0, &As[0][wid * 256]);
    glds16(AgS1, &As[0][wid * 256 + 2048]);
    glds16(BgS0, &Bs[0][wid * 512]);
    glds16(BgS1, &Bs[0][wid * 512 + 4096]);
    __syncthreads();

    #pragma unroll 1
    for (int kt = 0; kt < 16; ++kt) {
        const int cur = kt & 1;
        // issue next k-tile into the other buffer (zero-register async)
        if (kt < 15) {
            const int nxt = cur ^ 1;
            const int ko = (kt + 1) * 32;
            glds16(AgS0 + ko, &As[nxt][wid * 256]);
            glds16(AgS1 + ko, &As[nxt][wid * 256 + 2048]);
            glds16(BgS0 + ko, &Bs[nxt][wid * 512]);
            glds16(BgS1 + ko, &Bs[nxt][wid * 512 + 4096]);
        }
        // A frags: 2x ds_read_b128 + 4x cvt_pkrtz each
        f16x8 af[4];
        #pragma unroll
        for (int m = 0; m < 4; ++m) {
            const int rbase = (wm * 64 + m * 16 + fr) * 32;
            float4 lo = *(const float4*)&As[cur][rbase + axc0];
            float4 hi = *(const float4*)&As[cur][rbase + axc1];
            union { fp16x2 h2[4]; f16x8 v; } u;
            u.h2[0] = __builtin_amdgcn_cvt_pkrtz(lo.x, lo.y);
            u.h2[1] = __builtin_amdgcn_cvt_pkrtz(lo.z, lo.w);
            u.h2[2] = __builtin_amdgcn_cvt_pkrtz(hi.x, hi.y);
            u.h2[3] = __builtin_amdgcn_cvt_pkrtz(hi.z, hi.w);
            af[m] = u.v;
        }
        // B frags: 1x ds_read_b128 each
        f16x8 bf[4];
        #pragma unroll
        for (int n = 0; n < 4; ++n)
            bf[n] = *(const f16x8*)&Bs[cur][(wn * 64 + n * 16 + fr) * 32 + bxo];
        // MFMA cluster
        #pragma unroll
        for (int m = 0; m < 4; ++m)
            #pragma unroll
            for (int n = 0; n < 4; ++n)
                acc[m][n] = __builtin_amdgcn_mfma_f32_16x16x32_f16(af[m], bf[n], acc[m][n], 0, 0, 0);
        __syncthreads();   // drains glds (vmcnt) + LDS reads (lgkm)
    }

    // epilogue: tanh + weighted reduce over all 256 a-cols
    const float* weff  = ws_in + WEFF_OFF;
    const float* dterm = ws_in + DEC_OFF + batch * A_;
    float wj[4], dj[4];
    #pragma unroll
    for (int n = 0; n < 4; ++n) {
        int a = wn * 64 + n * 16 + fr;
        wj[n] = weff[a];
        dj[n] = dterm[a];
    }
    #pragma unroll
    for (int m = 0; m < 4; ++m) {
        #pragma unroll
        for (int r = 0; r < 4; ++r) {
            float v = 0.f;
            #pragma unroll
            for (int n = 0; n < 4; ++n) {
                float x = acc[m][n][r] + dj[n];
                float e = __expf(2.f * x);
                v += (1.f - 2.f / (e + 1.f)) * wj[n];   // tanh(x)
            }
            #pragma unroll
            for (int mask = 1; mask < 16; mask <<= 1)
                v += __shfl_xor(v, mask, 64);
            if (fr == 0)
                red[wn][wm * 64 + m * 16 + (kq << 2) + r] = v;
        }
    }
    __syncthreads();
    if (t < 128)
        energy[R0 + t] = red[0][t] + red[1][t] + red[2][t] + red[3][t];
}

// ---------------------------------------------------------------------------
// Monotonic recurrence as a stable affine scan:
//   T_j = a_j * T_{j-1} + prev_j,  a_j = clip(1-p_j, 1e-10, 1),  alpha_j = p_j*T_j
__global__ void ma_scan_kernel(const float* __restrict__ energy,
                               const float* __restrict__ noise,
                               const float* __restrict__ prev,
                               const float* __restrict__ v_bias,
                               const float* __restrict__ r,
                               float* __restrict__ alpha_out) {
    int b = blockIdx.x, t = threadIdx.x;   // 256 threads x 8 elems
    const float bias = v_bias[0] + r[0];
    int base = b * S_ + t * 8;
    float p[8], av[8], bv[8];
    #pragma unroll
    for (int i = 0; i < 8; ++i) {
        float e = energy[base + i] + bias + noise[base + i];
        float pi = 1.f / (1.f + expf(-e));
        p[i]  = pi;
        av[i] = fmaxf(1.f - pi, 1e-10f);
        bv[i] = prev[base + i];
    }
    float Ai = 1.f, Bi = 0.f;
    #pragma unroll
    for (int i = 0; i < 8; ++i) { Bi = av[i] * Bi + bv[i]; Ai *= av[i]; }
    int lane = t & 63;
    #pragma unroll
    for (int off = 1; off < 64; off <<= 1) {
        float Ap = __shfl_up(Ai, off, 64);
        float Bp = __shfl_up(Bi, off, 64);
        if (lane >= off) { Bi = Ai * Bp + Bi; Ai = Ai * Ap; }
    }
    __shared__ float wA[4], wB[4];
    int w = t >> 6;
    if (lane == 63) { wA[w] = Ai; wB[w] = Bi; }
    __syncthreads();
    float Ax = __shfl_up(Ai, 1, 64);
    float Bx = __shfl_up(Bi, 1, 64);
    if (lane == 0) { Ax = 1.f; Bx = 0.f; }
    float PwA = 1.f, PwB = 0.f;
    for (int q = 0; q < w; ++q) { PwB = wA[q] * PwB + wB[q]; PwA *= wA[q]; }
    float T = Ax * PwB + Bx;
    #pragma unroll
    for (int i = 0; i < 8; ++i) {
        T = av[i] * T + bv[i];
        alpha_out[base + i] = p[i] * T;
    }
}

// ---------------------------------------------------------------------------
// context partials over s-chunks of 128, float4 loads; cpart = 1 MB (L2-fit)
__global__ void ma_ctxpart_kernel(const float* __restrict__ enc,
                                  const float* __restrict__ alpha,
                                  float* __restrict__ cpart) {
    int b = blockIdx.x, sc = blockIdx.y, t = threadIdx.x;   // (32,16) x 256
    const int sp = t >> 7;          // row parity
    const int d4 = t & 127;         // float4 column
    const float4* e = (const float4*)(enc + ((size_t)b * S_ + sc * 128) * D_);
    const float* al = alpha + b * S_ + sc * 128;
    float4 acc = {0.f, 0.f, 0.f, 0.f};
    #pragma unroll 4
    for (int s = sp; s < 128; s += 2) {
        float a = al[s];
        float4 v = e[(size_t)s * 128 + d4];
        acc.x = fmaf(v.x, a, acc.x);
        acc.y = fmaf(v.y, a, acc.y);
        acc.z = fmaf(v.z, a, acc.z);
        acc.w = fmaf(v.w, a, acc.w);
    }
    __shared__ float4 sh[128];
    if (sp == 1) sh[d4] = acc;
    __syncthreads();
    if (sp == 0) {
        float4 o = sh[d4];
        acc.x += o.x; acc.y += o.y; acc.z += o.z; acc.w += o.w;
        ((float4*)(cpart + ((size_t)(sc * B_ + b)) * D_))[d4] = acc;
    }
}

// 32 blocks x 512 thr: each thread one d, 16 coalesced partials
__global__ void ma_ctxreduce_kernel(const float* __restrict__ cpart,
                                    float* __restrict__ ctx) {
    int b = blockIdx.x, d = threadIdx.x;   // 512 threads
    float s = 0.f;
    #pragma unroll
    for (int q = 0; q < 16; ++q) s += cpart[((size_t)(q * B_ + b)) * D_ + d];
    ctx[b * D_ + d] = s;
}

// ---------------------------------------------------------------------------
extern "C" void kernel_launch(void* const* d_in, const int* in_sizes, int n_in,
                              void* d_out, int out_size, void* d_ws, size_t ws_size,
                              hipStream_t stream) {
    const float* enc    = (const float*)d_in[0];
    const float* dec    = (const float*)d_in[1];
    const float* prev   = (const float*)d_in[2];
    const float* noise  = (const float*)d_in[3];
    const float* W      = (const float*)d_in[4];
    const float* V      = (const float*)d_in[5];
    const float* bvec   = (const float*)d_in[6];
    const float* v_w    = (const float*)d_in[7];
    const float* v_g    = (const float*)d_in[8];
    const float* v_bias = (const float*)d_in[9];
    const float* r      = (const float*)d_in[10];

    float* out = (float*)d_out;             // [0:16384) context, [16384:81920) alpha
    float* ws  = (float*)d_ws;
    float* alpha = out + B_ * D_;
    _Float16* W16 = (_Float16*)(ws + CTX_OFF);   // region reused by cpart later

    ma_prep_kernel<<<1 + B_ + 128, 256, 0, stream>>>(v_w, v_g, dec, V, bvec, W, W16, ws);
    ma_energy_mfma<<<512, 512, 0, stream>>>(enc, W16, ws, ws + EPART_OFF);
    ma_scan_kernel<<<B_, 256, 0, stream>>>(ws + EPART_OFF, noise, prev, v_bias, r, alpha);
    dim3 gc(B_, 16);
    ma_ctxpart_kernel<<<gc, 256, 0, stream>>>(enc, alpha, ws + CTX_OFF);
    ma_ctxreduce_kernel<<<B_, 512, 0, stream>>>(ws + CTX_OFF, out);
}